// Round 4
// baseline (905.152 us; speedup 1.0000x reference)
//
#include <hip/hip_runtime.h>

#define LCc 1024
#define LQq 512
#define BB  64
#define DDim 256

typedef __attribute__((ext_vector_type(8))) short bf16x8;
typedef __attribute__((ext_vector_type(4))) float f32x4;
typedef __attribute__((ext_vector_type(4))) unsigned short us4;
typedef __attribute__((ext_vector_type(8))) unsigned short us8;

static __device__ __forceinline__ unsigned short f2b(float f) {
  unsigned u = __builtin_bit_cast(unsigned, f);
  unsigned r = u + 0x7FFFu + ((u >> 16) & 1u);   // RNE to bf16
  return (unsigned short)(r >> 16);
}
static __device__ __forceinline__ bf16x8 ldb8(const unsigned short* p) {
  return *(const bf16x8*)p;
}
static __device__ __forceinline__ f32x4 MFMA16(bf16x8 a, bf16x8 b, f32x4 c) {
  return __builtin_amdgcn_mfma_f32_16x16x32_bf16(a, b, c, 0, 0, 0);
}
// async global->LDS, 16B per lane; LDS dest = base + lane*16 (HW-scattered)
static __device__ __forceinline__ void gload16(const unsigned short* g, unsigned short* l) {
  __builtin_amdgcn_global_load_lds(
      (const __attribute__((address_space(1))) unsigned int*)g,
      (__attribute__((address_space(3))) unsigned int*)l, 16, 0, 0);
}

// ---------------------------------------------------------------------------
// prep_CF: read C once -> Cw=bf16(C*w4mlu) (b,c,d); CT=bf16(C) (b,d,c);
//          rowAdd[b][c]=dot(C_row,w4C). grid (LC/64, B), 256 thr.
// ---------------------------------------------------------------------------
__global__ __launch_bounds__(256, 4) void prep_CF(const float* __restrict__ C,
    const float* __restrict__ w4C, const float* __restrict__ w4mlu,
    unsigned short* __restrict__ Cw, unsigned short* __restrict__ CT,
    float* __restrict__ rowAdd) {
  __shared__ unsigned short tile[64][65];
  int c0 = blockIdx.x * 64, b = blockIdx.y;
  int t = threadIdx.x, r = t >> 2, g = t & 3;
  float rsum = 0.f;
  for (int dch = 0; dch < 4; dch++) {
    int d0 = dch * 64;
    const float* src = C + ((size_t)(c0 + r) * BB + b) * DDim + d0 + g * 16;
    unsigned short cwv[16];
    #pragma unroll
    for (int i = 0; i < 4; i++) {
      float4 v = ((const float4*)src)[i];
      float4 wm = *(const float4*)(w4mlu + d0 + g * 16 + i * 4);
      float4 wc = *(const float4*)(w4C + d0 + g * 16 + i * 4);
      rsum += v.x * wc.x + v.y * wc.y + v.z * wc.z + v.w * wc.w;
      cwv[i * 4 + 0] = f2b(v.x * wm.x);
      cwv[i * 4 + 1] = f2b(v.y * wm.y);
      cwv[i * 4 + 2] = f2b(v.z * wm.z);
      cwv[i * 4 + 3] = f2b(v.w * wm.w);
      tile[r][g * 16 + i * 4 + 0] = f2b(v.x);
      tile[r][g * 16 + i * 4 + 1] = f2b(v.y);
      tile[r][g * 16 + i * 4 + 2] = f2b(v.z);
      tile[r][g * 16 + i * 4 + 3] = f2b(v.w);
    }
    unsigned short* cwp = Cw + ((size_t)((b << 10) + c0 + r)) * DDim + d0 + g * 16;
    *(us8*)cwp = *(us8*)&cwv[0];
    *(us8*)(cwp + 8) = *(us8*)&cwv[8];
    __syncthreads();
    // CT rows d0+r, cols c0+g*16..+15
    unsigned short* ctp = CT + ((size_t)((b << 8) + d0 + r)) * LCc + c0 + g * 16;
    us8 o0, o1;
    #pragma unroll
    for (int j = 0; j < 8; j++) { o0[j] = tile[g * 16 + j][r]; o1[j] = tile[g * 16 + 8 + j][r]; }
    *(us8*)ctp = o0;
    *(us8*)(ctp + 8) = o1;
    __syncthreads();
  }
  rsum += __shfl_xor(rsum, 1);
  rsum += __shfl_xor(rsum, 2);
  if (g == 0) rowAdd[((size_t)b << 10) + c0 + r] = rsum;
}

// ---------------------------------------------------------------------------
// prep_QF: read Q once -> Qb=bf16(Q) (b,q,d); QT=bf16(Q) (b,d,q);
//          colAdd=dot(Q_row,w4Q)+bias; colL=0. grid (LQ/64, B).
// ---------------------------------------------------------------------------
__global__ __launch_bounds__(256, 4) void prep_QF(const float* __restrict__ Q,
    const float* __restrict__ w4Q, const float* __restrict__ bias,
    unsigned short* __restrict__ Qb, unsigned short* __restrict__ QT,
    float* __restrict__ colAdd, float* __restrict__ colL) {
  __shared__ unsigned short tile[64][65];
  int q0 = blockIdx.x * 64, b = blockIdx.y;
  int t = threadIdx.x, r = t >> 2, g = t & 3;
  float rsum = 0.f;
  for (int dch = 0; dch < 4; dch++) {
    int d0 = dch * 64;
    const float* src = Q + ((size_t)(q0 + r) * BB + b) * DDim + d0 + g * 16;
    #pragma unroll
    for (int i = 0; i < 4; i++) {
      float4 v = ((const float4*)src)[i];
      float4 wq = *(const float4*)(w4Q + d0 + g * 16 + i * 4);
      rsum += v.x * wq.x + v.y * wq.y + v.z * wq.z + v.w * wq.w;
      tile[r][g * 16 + i * 4 + 0] = f2b(v.x);
      tile[r][g * 16 + i * 4 + 1] = f2b(v.y);
      tile[r][g * 16 + i * 4 + 2] = f2b(v.z);
      tile[r][g * 16 + i * 4 + 3] = f2b(v.w);
    }
    __syncthreads();
    unsigned short* qbp = Qb + ((size_t)((b << 9) + q0 + r)) * DDim + d0 + g * 16;
    us8 s0, s1;
    #pragma unroll
    for (int j = 0; j < 8; j++) { s0[j] = tile[r][g * 16 + j]; s1[j] = tile[r][g * 16 + 8 + j]; }
    *(us8*)qbp = s0;
    *(us8*)(qbp + 8) = s1;
    unsigned short* qtp = QT + ((size_t)((b << 8) + d0 + r)) * LQq + q0 + g * 16;
    us8 o0, o1;
    #pragma unroll
    for (int j = 0; j < 8; j++) { o0[j] = tile[g * 16 + j][r]; o1[j] = tile[g * 16 + 8 + j][r]; }
    *(us8*)qtp = o0;
    *(us8*)(qtp + 8) = o1;
    __syncthreads();
  }
  rsum += __shfl_xor(rsum, 1);
  rsum += __shfl_xor(rsum, 2);
  if (g == 0) {
    colAdd[((size_t)b << 9) + q0 + r] = rsum + bias[0];
    colL[((size_t)b << 9) + q0 + r] = 0.0f;
  }
}

// ---------------------------------------------------------------------------
// k_P: E = exp(Cw@Qb^T + rowAdd + colAdd) stored as fragment-ready tiles
//      Ptiles[((b*64+cb)*16+qs)*512 + lane*8]; rowL direct; colL atomic.
// grid B*16 XCD-swizzled (all 16 blocks of a b on one XCD for Qb L2 reuse),
// 4 waves, wave w -> c-band w.
// ---------------------------------------------------------------------------
__global__ __launch_bounds__(256, 3) void k_P(const unsigned short* __restrict__ Cw,
    const unsigned short* __restrict__ Qb, const float* __restrict__ rowAdd,
    const float* __restrict__ colAdd, unsigned short* __restrict__ Pt,
    float* __restrict__ rowL, float* __restrict__ colL) {
  int idx = blockIdx.x;
  int xcd = idx & 7, loc = idx >> 3;
  int b = xcd * 8 + (loc >> 4), ct = loc & 15;
  int t = threadIdx.x, w = t >> 6, lane = t & 63;
  int col = lane & 15, quad = lane >> 4;
  int c0w = ct * 64 + w * 16;
  __shared__ unsigned short tile[2][64][40];   // [buf][c-local 64][q-window 32 pad 40]
  __shared__ float colAcc[LQq];
  for (int i = t; i < LQq; i += 256) colAcc[i] = 0.f;
  __syncthreads();

  bf16x8 afrag[8];
  const unsigned short* aPtr = Cw + ((size_t)((b << 10) + c0w + col)) * DDim + quad * 8;
  #pragma unroll
  for (int kk = 0; kk < 8; kk++) afrag[kk] = ldb8(aPtr + kk * 32);
  float rAddv[4];
  #pragma unroll
  for (int r = 0; r < 4; r++) rAddv[r] = rowAdd[((size_t)b << 10) + c0w + quad * 4 + r];
  float rowSum[4] = {0.f, 0.f, 0.f, 0.f};

  int cur = 0;
  for (int win = 0; win < 16; win++) {
    #pragma unroll
    for (int h = 0; h < 2; h++) {
      int q0 = win * 32 + h * 16;
      const unsigned short* bPtr = Qb + ((size_t)((b << 9) + q0 + col)) * DDim + quad * 8;
      f32x4 acc = {0.f, 0.f, 0.f, 0.f};
      #pragma unroll
      for (int kk = 0; kk < 8; kk++) acc = MFMA16(afrag[kk], ldb8(bPtr + kk * 32), acc);
      float cAdd = colAdd[((size_t)b << 9) + q0 + col];
      float csum = 0.f;
      #pragma unroll
      for (int r = 0; r < 4; r++) {
        float e = __expf(acc[r] + rAddv[r] + cAdd);
        rowSum[r] += e;
        csum += e;
        tile[cur][w * 16 + quad * 4 + r][h * 16 + col] = f2b(e);
      }
      csum += __shfl_xor(csum, 16);
      csum += __shfl_xor(csum, 32);
      if (lane < 16) atomicAdd(&colAcc[q0 + lane], csum);
    }
    __syncthreads();
    // assemble + store this window's P tile for band w (1 KB, coalesced)
    us8 frag = *(const us8*)&tile[cur][w * 16 + col][quad * 8];
    *(us8*)(Pt + (((size_t)(b * 64 + ct * 4 + w) * 16 + win) << 9) + lane * 8) = frag;
    cur ^= 1;
  }
  #pragma unroll
  for (int r = 0; r < 4; r++) {
    float s = rowSum[r];
    s += __shfl_xor(s, 1); s += __shfl_xor(s, 2);
    s += __shfl_xor(s, 4); s += __shfl_xor(s, 8);
    if (col == 0) rowL[((size_t)b << 10) + c0w + quad * 4 + r] = s;
  }
  __syncthreads();
  for (int i = t; i < LQq; i += 256) atomicAdd(&colL[((size_t)b << 9) + i], colAcc[i]);
}

// ---------------------------------------------------------------------------
// k_T: TT[b][d][q] = bf16( sum_c E[c][q]/colL[q] * C[c][d] )
// grid B*16 XCD-swizzled (CT reuse), 4 waves; wave w -> d-quarter w*64.
// A-frags via tiny cooperative LDS transpose of P tiles; B = CT streaming.
// ---------------------------------------------------------------------------
__global__ __launch_bounds__(256, 4) void k_T(const unsigned short* __restrict__ Pt,
    const unsigned short* __restrict__ CT, const float* __restrict__ colL,
    unsigned short* __restrict__ TT) {
  int idx = blockIdx.x;
  int xcd = idx & 7, loc = idx >> 3;
  int b = xcd * 8 + (loc >> 4), qs = loc & 15;
  int t = threadIdx.x, w = t >> 6, lane = t & 63;
  int col = lane & 15, quad = lane >> 4;
  int dq = w * 64;
  int cbl = w & 1, jh = w >> 1;     // this wave's transform share
  __shared__ unsigned short pT[32][40];   // [q-local 32][c-chunk 32 pad 40]

  f32x4 accT[2][4];
  #pragma unroll
  for (int mf = 0; mf < 2; mf++)
    #pragma unroll
    for (int nf = 0; nf < 4; nf++) accT[mf][nf] = (f32x4){0.f, 0.f, 0.f, 0.f};

  us8 frag = *(const us8*)(Pt + (((size_t)(b * 64 + 0 * 2 + cbl) * 16 + qs) << 9) + lane * 8);
  for (int cs = 0; cs < 32; cs++) {
    bf16x8 bf[4];
    #pragma unroll
    for (int nf = 0; nf < 4; nf++)
      bf[nf] = ldb8(CT + ((size_t)((b << 8) + dq + nf * 16 + col)) * LCc + cs * 32 + quad * 8);
    // write this wave's quarter of the 32x32 transpose chunk
    #pragma unroll
    for (int jj = 0; jj < 4; jj++) {
      int j = jh * 4 + jj;
      pT[quad * 8 + j][cbl * 16 + col] = (unsigned short)frag[j];
    }
    __syncthreads();
    bf16x8 pa[2];
    #pragma unroll
    for (int mf = 0; mf < 2; mf++) pa[mf] = *(const bf16x8*)&pT[mf * 16 + col][quad * 8];
    #pragma unroll
    for (int mf = 0; mf < 2; mf++)
      #pragma unroll
      for (int nf = 0; nf < 4; nf++) accT[mf][nf] = MFMA16(pa[mf], bf[nf], accT[mf][nf]);
    if (cs < 31)
      frag = *(const us8*)(Pt + (((size_t)(b * 64 + (cs + 1) * 2 + cbl) * 16 + qs) << 9) + lane * 8);
    __syncthreads();
  }
  float cInv[2][4];
  #pragma unroll
  for (int mf = 0; mf < 2; mf++)
    #pragma unroll
    for (int r = 0; r < 4; r++)
      cInv[mf][r] = 1.0f / colL[((size_t)b << 9) + qs * 32 + mf * 16 + quad * 4 + r];
  #pragma unroll
  for (int mf = 0; mf < 2; mf++)
    #pragma unroll
    for (int nf = 0; nf < 4; nf++) {
      us4 ov;
      #pragma unroll
      for (int r = 0; r < 4; r++) ov[r] = f2b(accT[mf][nf][r] * cInv[mf][r]);
      *(us4*)(TT + ((size_t)((b << 8) + dq + nf * 16 + col)) * LQq + qs * 32 + mf * 16 + quad * 4) = ov;
    }
}

// ---------------------------------------------------------------------------
// k_AB: A = (E/rowL)@Q, B = (E/rowL)@T; fused epilogue -> out (B,4D,LC).
// v4: occupancy-first. c-tile 32 (grid B*32, XCD-swizzled), acc halved ->
// ~115 VGPR, 4 waves/EU; single-buffer LDS 32 KiB (sb wave-private, WAR
// guarded by lgkmcnt(0) between ds_reads and next STAGE); zero barriers;
// Pt ping-pong depth-2; exact counted vmcnt(2) (tail 0).
// Issue order/iter: wait vmcnt -> ds_read(bq,bt) -> lgkmcnt(0) ->
//   STAGE(qs+1) -> MFMA -> PTLOAD(qs+2).
// ---------------------------------------------------------------------------
__global__ __launch_bounds__(256, 4) void k_AB(const unsigned short* __restrict__ Pt,
    const unsigned short* __restrict__ QT, const unsigned short* __restrict__ TT,
    const float* __restrict__ rowL, const float* __restrict__ C,
    float* __restrict__ out) {
  int idx = blockIdx.x;
  int xcd = idx & 7, loc = idx >> 3;
  int b = xcd * 8 + (loc >> 5), ct = loc & 31;   // ct: c-tile of 32 rows
  int t = threadIdx.x, w = t >> 6, lane = t & 63;
  int col = lane & 15, quad = lane >> 4;
  int dq = w * 64;
  __shared__ unsigned short sb[4][8][512];   // 32 KiB: wave x 8 slabs x 1KB

  f32x4 accA[2][4], accB[2][4];
  #pragma unroll
  for (int mf = 0; mf < 2; mf++)
    #pragma unroll
    for (int nf = 0; nf < 4; nf++) {
      accA[mf][nf] = (f32x4){0.f, 0.f, 0.f, 0.f};
      accB[mf][nf] = (f32x4){0.f, 0.f, 0.f, 0.f};
    }

  // stage(qs): 8 async wave-loads; lane (col,quad) fetches 16B of row
  // (dq+nf*16+col) chunk quad -> LDS identity lane*16 (conflict-free map).
  #define STAGE(qs_)                                                                    \
    {                                                                                   \
      int _q = (qs_) * 32 + quad * 8;                                                   \
      _Pragma("unroll")                                                                 \
      for (int nf = 0; nf < 4; nf++) {                                                  \
        size_t rowD = (size_t)((b << 8) + dq + nf * 16 + col);                          \
        gload16(QT + (rowD << 9) + _q, &sb[w][nf][0]);                                  \
        gload16(TT + (rowD << 9) + _q, &sb[w][4 + nf][0]);                              \
      }                                                                                 \
    }
  #define PTLOAD(qs_, set_)                                                             \
    {                                                                                   \
      _Pragma("unroll")                                                                 \
      for (int mf = 0; mf < 2; mf++)                                                    \
        pa[set_][mf] = ldb8(ptB + mf * 8192 + (qs_) * 512);                             \
    }
  #define SBAR __builtin_amdgcn_sched_barrier(0)

  // Pt tile index cb = b*64 + ct*2 + mf
  const unsigned short* ptB = Pt + (((size_t)(b * 64 + ct * 2) * 16) << 9) + lane * 8;
  bf16x8 pa[2][2];

  // prologue: S(0), P(0), P(1)  (12 VMEM ops, order pinned)
  SBAR;
  STAGE(0);
  SBAR;
  PTLOAD(0, 0);
  SBAR;
  PTLOAD(1, 1);
  SBAR;

  #pragma unroll
  for (int qs = 0; qs < 16; qs++) {
    // drain S(qs)+P(qs); leave P(qs+1) (2 ops) in flight
    if (qs < 15) asm volatile("s_waitcnt vmcnt(2)" ::: "memory");
    else         asm volatile("s_waitcnt vmcnt(0)" ::: "memory");
    SBAR;
    bf16x8 bq[4], bt[4];
    #pragma unroll
    for (int nf = 0; nf < 4; nf++) {
      bq[nf] = ldb8(&sb[w][nf][lane * 8]);
      bt[nf] = ldb8(&sb[w][4 + nf][lane * 8]);
    }
    asm volatile("s_waitcnt lgkmcnt(0)" ::: "memory");   // frags in regs; buffer free
    SBAR;
    if (qs < 15) { STAGE(qs + 1); }   // overwrite single buffer (WAR-safe now)
    SBAR;
    #pragma unroll
    for (int mf = 0; mf < 2; mf++)
      #pragma unroll
      for (int nf = 0; nf < 4; nf++) {
        accA[mf][nf] = MFMA16(pa[qs & 1][mf], bq[nf], accA[mf][nf]);
        accB[mf][nf] = MFMA16(pa[qs & 1][mf], bt[nf], accB[mf][nf]);
      }
    SBAR;
    if (qs < 14) { PTLOAD(qs + 2, qs & 1); }   // reuse the set just consumed
    SBAR;
  }

  // epilogue: scale by 1/rowL, multiply with C, write 4 chunks transposed
  float rInv[2][4];
  #pragma unroll
  for (int mf = 0; mf < 2; mf++) {
    float4 rv = *(const float4*)(rowL + ((size_t)b << 10) + ct * 32 + mf * 16 + quad * 4);
    rInv[mf][0] = 1.0f / rv.x; rInv[mf][1] = 1.0f / rv.y;
    rInv[mf][2] = 1.0f / rv.z; rInv[mf][3] = 1.0f / rv.w;
  }
  size_t outB = (size_t)b << 20;
  #pragma unroll
  for (int mf = 0; mf < 2; mf++) {
    int cc = ct * 32 + mf * 16 + quad * 4;
    #pragma unroll
    for (int nf = 0; nf < 4; nf++) {
      int d = dq + nf * 16 + col;
      float4 vC, vA, vCA, vCB;
      #pragma unroll
      for (int r = 0; r < 4; r++) {
        float Cv = C[((size_t)(cc + r) * BB + b) * DDim + d];
        float Av = accA[mf][nf][r] * rInv[mf][r];
        float Bv = accB[mf][nf][r] * rInv[mf][r];
        ((float*)&vC)[r] = Cv;
        ((float*)&vA)[r] = Av;
        ((float*)&vCA)[r] = Cv * Av;
        ((float*)&vCB)[r] = Cv * Bv;
      }
      float* o0 = out + outB + (size_t)d * LCc + cc;
      *(float4*)(o0) = vC;
      *(float4*)(o0 + (size_t)DDim * LCc) = vA;
      *(float4*)(o0 + 2 * (size_t)DDim * LCc) = vCA;
      *(float4*)(o0 + 3 * (size_t)DDim * LCc) = vCB;
    }
  }
  #undef STAGE
  #undef PTLOAD
  #undef SBAR
}

// ---------------------------------------------------------------------------
extern "C" void kernel_launch(void* const* d_in, const int* in_sizes, int n_in,
                              void* d_out, int out_size, void* d_ws, size_t ws_size,
                              hipStream_t stream) {
  const float* C    = (const float*)d_in[0];
  const float* Q    = (const float*)d_in[1];
  const float* w4C  = (const float*)d_in[2];
  const float* w4Q  = (const float*)d_in[3];
  const float* w4mlu= (const float*)d_in[4];
  const float* bias = (const float*)d_in[5];
  float* out = (float*)d_out;
  char* ws = (char*)d_ws;

  // workspace layout (~161 MiB; TT aliases Qb — Qb dead after k_P)
  unsigned short* Cw = (unsigned short*)(ws);                       // 33554432
  unsigned short* CT = (unsigned short*)(ws + 33554432);            // 33554432
  unsigned short* Qb = (unsigned short*)(ws + 67108864);            // 16777216
  unsigned short* TT = Qb;                                          // alias
  unsigned short* QT = (unsigned short*)(ws + 83886080);            // 16777216
  unsigned short* Pt = (unsigned short*)(ws + 100663296);           // 67108864
  float* rowAdd = (float*)(ws + 167772160);                         //   262144
  float* colAdd = (float*)(ws + 168034304);                         //   131072
  float* rowL   = (float*)(ws + 168165376);                         //   262144
  float* colL   = (float*)(ws + 168427520);                         //   131072

  prep_CF<<<dim3(LCc / 64, BB), 256, 0, stream>>>(C, w4C, w4mlu, Cw, CT, rowAdd);
  prep_QF<<<dim3(LQq / 64, BB), 256, 0, stream>>>(Q, w4Q, bias, Qb, QT, colAdd, colL);
  k_P<<<BB * 16, 256, 0, stream>>>(Cw, Qb, rowAdd, colAdd, Pt, rowL, colL);
  k_T<<<BB * 16, 256, 0, stream>>>(Pt, CT, colL, TT);
  k_AB<<<BB * 32, 256, 0, stream>>>(Pt, QT, TT, rowL, C, out);
}

// Round 5
// 681.366 us; speedup vs baseline: 1.3284x; 1.3284x over previous
//
#include <hip/hip_runtime.h>

#define LCc 1024
#define LQq 512
#define BB  64
#define DDim 256

typedef __attribute__((ext_vector_type(8))) short bf16x8;
typedef __attribute__((ext_vector_type(4))) float f32x4;
typedef __attribute__((ext_vector_type(4))) unsigned short us4;
typedef __attribute__((ext_vector_type(8))) unsigned short us8;

static __device__ __forceinline__ unsigned short f2b(float f) {
  unsigned u = __builtin_bit_cast(unsigned, f);
  unsigned r = u + 0x7FFFu + ((u >> 16) & 1u);   // RNE to bf16
  return (unsigned short)(r >> 16);
}
static __device__ __forceinline__ bf16x8 ldb8(const unsigned short* p) {
  return *(const bf16x8*)p;
}
static __device__ __forceinline__ f32x4 MFMA16(bf16x8 a, bf16x8 b, f32x4 c) {
  return __builtin_amdgcn_mfma_f32_16x16x32_bf16(a, b, c, 0, 0, 0);
}
// async global->LDS, 16B per lane; LDS dest = base + lane*16 (HW-scattered)
static __device__ __forceinline__ void gload16(const unsigned short* g, unsigned short* l) {
  __builtin_amdgcn_global_load_lds(
      (const __attribute__((address_space(1))) unsigned int*)g,
      (__attribute__((address_space(3))) unsigned int*)l, 16, 0, 0);
}

// ---------------------------------------------------------------------------
// prep_F: fused prep. blocks x<16: C-side (Cw, CT, rowAdd); x>=16: Q-side
// (Qb, QT, colAdd, colL). Fusion overlaps the two formerly-serial dispatches.
// grid (24, B), 256 thr.
// ---------------------------------------------------------------------------
__global__ __launch_bounds__(256, 4) void prep_F(const float* __restrict__ C,
    const float* __restrict__ Q, const float* __restrict__ w4C,
    const float* __restrict__ w4Q, const float* __restrict__ w4mlu,
    const float* __restrict__ bias,
    unsigned short* __restrict__ Cw, unsigned short* __restrict__ CT,
    float* __restrict__ rowAdd,
    unsigned short* __restrict__ Qb, unsigned short* __restrict__ QT,
    float* __restrict__ colAdd, float* __restrict__ colL) {
  __shared__ unsigned short tile[64][65];
  int b = blockIdx.y;
  int t = threadIdx.x, r = t >> 2, g = t & 3;
  float rsum = 0.f;
  if (blockIdx.x < 16) {
    int c0 = blockIdx.x * 64;
    for (int dch = 0; dch < 4; dch++) {
      int d0 = dch * 64;
      const float* src = C + ((size_t)(c0 + r) * BB + b) * DDim + d0 + g * 16;
      unsigned short cwv[16];
      #pragma unroll
      for (int i = 0; i < 4; i++) {
        float4 v = ((const float4*)src)[i];
        float4 wm = *(const float4*)(w4mlu + d0 + g * 16 + i * 4);
        float4 wc = *(const float4*)(w4C + d0 + g * 16 + i * 4);
        rsum += v.x * wc.x + v.y * wc.y + v.z * wc.z + v.w * wc.w;
        cwv[i * 4 + 0] = f2b(v.x * wm.x);
        cwv[i * 4 + 1] = f2b(v.y * wm.y);
        cwv[i * 4 + 2] = f2b(v.z * wm.z);
        cwv[i * 4 + 3] = f2b(v.w * wm.w);
        tile[r][g * 16 + i * 4 + 0] = f2b(v.x);
        tile[r][g * 16 + i * 4 + 1] = f2b(v.y);
        tile[r][g * 16 + i * 4 + 2] = f2b(v.z);
        tile[r][g * 16 + i * 4 + 3] = f2b(v.w);
      }
      unsigned short* cwp = Cw + ((size_t)((b << 10) + c0 + r)) * DDim + d0 + g * 16;
      *(us8*)cwp = *(us8*)&cwv[0];
      *(us8*)(cwp + 8) = *(us8*)&cwv[8];
      __syncthreads();
      unsigned short* ctp = CT + ((size_t)((b << 8) + d0 + r)) * LCc + c0 + g * 16;
      us8 o0, o1;
      #pragma unroll
      for (int j = 0; j < 8; j++) { o0[j] = tile[g * 16 + j][r]; o1[j] = tile[g * 16 + 8 + j][r]; }
      *(us8*)ctp = o0;
      *(us8*)(ctp + 8) = o1;
      __syncthreads();
    }
    rsum += __shfl_xor(rsum, 1);
    rsum += __shfl_xor(rsum, 2);
    if (g == 0) rowAdd[((size_t)b << 10) + c0 + r] = rsum;
  } else {
    int q0 = (blockIdx.x - 16) * 64;
    for (int dch = 0; dch < 4; dch++) {
      int d0 = dch * 64;
      const float* src = Q + ((size_t)(q0 + r) * BB + b) * DDim + d0 + g * 16;
      #pragma unroll
      for (int i = 0; i < 4; i++) {
        float4 v = ((const float4*)src)[i];
        float4 wq = *(const float4*)(w4Q + d0 + g * 16 + i * 4);
        rsum += v.x * wq.x + v.y * wq.y + v.z * wq.z + v.w * wq.w;
        tile[r][g * 16 + i * 4 + 0] = f2b(v.x);
        tile[r][g * 16 + i * 4 + 1] = f2b(v.y);
        tile[r][g * 16 + i * 4 + 2] = f2b(v.z);
        tile[r][g * 16 + i * 4 + 3] = f2b(v.w);
      }
      __syncthreads();
      unsigned short* qbp = Qb + ((size_t)((b << 9) + q0 + r)) * DDim + d0 + g * 16;
      us8 s0, s1;
      #pragma unroll
      for (int j = 0; j < 8; j++) { s0[j] = tile[r][g * 16 + j]; s1[j] = tile[r][g * 16 + 8 + j]; }
      *(us8*)qbp = s0;
      *(us8*)(qbp + 8) = s1;
      unsigned short* qtp = QT + ((size_t)((b << 8) + d0 + r)) * LQq + q0 + g * 16;
      us8 o0, o1;
      #pragma unroll
      for (int j = 0; j < 8; j++) { o0[j] = tile[g * 16 + j][r]; o1[j] = tile[g * 16 + 8 + j][r]; }
      *(us8*)qtp = o0;
      *(us8*)(qtp + 8) = o1;
      __syncthreads();
    }
    rsum += __shfl_xor(rsum, 1);
    rsum += __shfl_xor(rsum, 2);
    if (g == 0) {
      colAdd[((size_t)b << 9) + q0 + r] = rsum + bias[0];
      colL[((size_t)b << 9) + q0 + r] = 0.0f;
    }
  }
}

// ---------------------------------------------------------------------------
// k_P: E = exp(Cw@Qb^T + rowAdd + colAdd) stored as fragment-ready tiles
//      Ptiles[((b*64+cb)*16+qs)*512 + lane*8]; rowL direct; colL atomic.
// grid B*16, chunked-XCD swizzle: xcd=idx&7 owns b in [xcd*8, xcd*8+8),
// 16 ct-blocks of a b consecutive -> Qb panel (256KB) L2-resident per b.
// 4 waves, wave w -> c-band w.
// ---------------------------------------------------------------------------
__global__ __launch_bounds__(256, 3) void k_P(const unsigned short* __restrict__ Cw,
    const unsigned short* __restrict__ Qb, const float* __restrict__ rowAdd,
    const float* __restrict__ colAdd, unsigned short* __restrict__ Pt,
    float* __restrict__ rowL, float* __restrict__ colL) {
  int idx = blockIdx.x;
  int xcd = idx & 7, jj = idx >> 3;
  int b = xcd * 8 + (jj >> 4), ct = jj & 15;
  int t = threadIdx.x, w = t >> 6, lane = t & 63;
  int col = lane & 15, quad = lane >> 4;
  int c0w = ct * 64 + w * 16;
  __shared__ unsigned short tile[2][64][40];   // [buf][c-local 64][q-window 32 pad 40]
  __shared__ float colAcc[LQq];
  for (int i = t; i < LQq; i += 256) colAcc[i] = 0.f;
  __syncthreads();

  bf16x8 afrag[8];
  const unsigned short* aPtr = Cw + ((size_t)((b << 10) + c0w + col)) * DDim + quad * 8;
  #pragma unroll
  for (int kk = 0; kk < 8; kk++) afrag[kk] = ldb8(aPtr + kk * 32);
  float rAddv[4];
  #pragma unroll
  for (int r = 0; r < 4; r++) rAddv[r] = rowAdd[((size_t)b << 10) + c0w + quad * 4 + r];
  float rowSum[4] = {0.f, 0.f, 0.f, 0.f};

  int cur = 0;
  for (int win = 0; win < 16; win++) {
    #pragma unroll
    for (int h = 0; h < 2; h++) {
      int q0 = win * 32 + h * 16;
      const unsigned short* bPtr = Qb + ((size_t)((b << 9) + q0 + col)) * DDim + quad * 8;
      f32x4 acc = {0.f, 0.f, 0.f, 0.f};
      #pragma unroll
      for (int kk = 0; kk < 8; kk++) acc = MFMA16(afrag[kk], ldb8(bPtr + kk * 32), acc);
      float cAdd = colAdd[((size_t)b << 9) + q0 + col];
      float csum = 0.f;
      #pragma unroll
      for (int r = 0; r < 4; r++) {
        float e = __expf(acc[r] + rAddv[r] + cAdd);
        rowSum[r] += e;
        csum += e;
        tile[cur][w * 16 + quad * 4 + r][h * 16 + col] = f2b(e);
      }
      csum += __shfl_xor(csum, 16);
      csum += __shfl_xor(csum, 32);
      if (lane < 16) atomicAdd(&colAcc[q0 + lane], csum);
    }
    __syncthreads();
    // assemble + store this window's P tile for band w (1 KB, coalesced)
    us8 frag = *(const us8*)&tile[cur][w * 16 + col][quad * 8];
    *(us8*)(Pt + (((size_t)(b * 64 + ct * 4 + w) * 16 + win) << 9) + lane * 8) = frag;
    cur ^= 1;
  }
  #pragma unroll
  for (int r = 0; r < 4; r++) {
    float s = rowSum[r];
    s += __shfl_xor(s, 1); s += __shfl_xor(s, 2);
    s += __shfl_xor(s, 4); s += __shfl_xor(s, 8);
    if (col == 0) rowL[((size_t)b << 10) + c0w + quad * 4 + r] = s;
  }
  __syncthreads();
  for (int i = t; i < LQq; i += 256) atomicAdd(&colL[((size_t)b << 9) + i], colAcc[i]);
}

// ---------------------------------------------------------------------------
// k_T: TT[b][d][q] = bf16( sum_c E[c][q]/colL[q] * C[c][d] )
// grid B*16 chunked-XCD swizzle (CT panel 512KB L2-resident per b),
// 4 waves; wave w -> d-quarter w*64.
// v5: double-buffered pT -> ONE barrier per cs (was 2): write pT[cs&1],
// barrier, read pT[cs&1]; next write targets pT[cs^1] (disjoint, skew-safe).
// ---------------------------------------------------------------------------
__global__ __launch_bounds__(256, 4) void k_T(const unsigned short* __restrict__ Pt,
    const unsigned short* __restrict__ CT, const float* __restrict__ colL,
    unsigned short* __restrict__ TT) {
  int idx = blockIdx.x;
  int xcd = idx & 7, jj = idx >> 3;
  int b = xcd * 8 + (jj >> 4), qs = jj & 15;
  int t = threadIdx.x, w = t >> 6, lane = t & 63;
  int col = lane & 15, quad = lane >> 4;
  int dq = w * 64;
  int cbl = w & 1, jh = w >> 1;     // this wave's transform share
  __shared__ unsigned short pT[2][32][40];   // [buf][q-local 32][c-chunk 32 pad 40]

  f32x4 accT[2][4];
  #pragma unroll
  for (int mf = 0; mf < 2; mf++)
    #pragma unroll
    for (int nf = 0; nf < 4; nf++) accT[mf][nf] = (f32x4){0.f, 0.f, 0.f, 0.f};

  us8 frag = *(const us8*)(Pt + (((size_t)(b * 64 + 0 * 2 + cbl) * 16 + qs) << 9) + lane * 8);
  for (int cs = 0; cs < 32; cs++) {
    bf16x8 bf[4];
    #pragma unroll
    for (int nf = 0; nf < 4; nf++)
      bf[nf] = ldb8(CT + ((size_t)((b << 8) + dq + nf * 16 + col)) * LCc + cs * 32 + quad * 8);
    // write this wave's quarter of the 32x32 transpose chunk
    #pragma unroll
    for (int j2 = 0; j2 < 4; j2++) {
      int j = jh * 4 + j2;
      pT[cs & 1][quad * 8 + j][cbl * 16 + col] = (unsigned short)frag[j];
    }
    us8 fragN;
    if (cs < 31)
      fragN = *(const us8*)(Pt + (((size_t)(b * 64 + (cs + 1) * 2 + cbl) * 16 + qs) << 9) + lane * 8);
    __syncthreads();
    bf16x8 pa[2];
    #pragma unroll
    for (int mf = 0; mf < 2; mf++) pa[mf] = *(const bf16x8*)&pT[cs & 1][mf * 16 + col][quad * 8];
    #pragma unroll
    for (int mf = 0; mf < 2; mf++)
      #pragma unroll
      for (int nf = 0; nf < 4; nf++) accT[mf][nf] = MFMA16(pa[mf], bf[nf], accT[mf][nf]);
    frag = fragN;
  }
  float cInv[2][4];
  #pragma unroll
  for (int mf = 0; mf < 2; mf++)
    #pragma unroll
    for (int r = 0; r < 4; r++)
      cInv[mf][r] = 1.0f / colL[((size_t)b << 9) + qs * 32 + mf * 16 + quad * 4 + r];
  #pragma unroll
  for (int mf = 0; mf < 2; mf++)
    #pragma unroll
    for (int nf = 0; nf < 4; nf++) {
      us4 ov;
      #pragma unroll
      for (int r = 0; r < 4; r++) ov[r] = f2b(accT[mf][nf][r] * cInv[mf][r]);
      *(us4*)(TT + ((size_t)((b << 8) + dq + nf * 16 + col)) * LQq + qs * 32 + mf * 16 + quad * 4) = ov;
    }
}

// ---------------------------------------------------------------------------
// k_AB: A = (E/rowL)@Q, B = (E/rowL)@T; fused epilogue -> out (B,4D,LC).
// v5: EXACT round-0 body (measured best, 170us) + chunked-XCD swizzle:
// the 16 blocks of each b consecutive on one XCD -> ~4 concurrent b's/XCD
// = 4MB QT+TT working set, L2-resident (round-4's interleaved swizzle put
// 8MB/XCD -> thrashed; this is the fix).
// ---------------------------------------------------------------------------
__global__ __launch_bounds__(256, 2) void k_AB(const unsigned short* __restrict__ Pt,
    const unsigned short* __restrict__ QT, const unsigned short* __restrict__ TT,
    const float* __restrict__ rowL, const float* __restrict__ C,
    float* __restrict__ out) {
  int idx = blockIdx.x;
  int xcd = idx & 7, jj = idx >> 3;
  int b = xcd * 8 + (jj >> 4), ct = jj & 15;
  int t = threadIdx.x, w = t >> 6, lane = t & 63;
  int col = lane & 15, quad = lane >> 4;
  int dq = w * 64;
  __shared__ unsigned short sb[4][2][8][512];   // 64 KiB: wave x dbuf x 8 slabs x 1KB

  f32x4 accA[4][4], accB[4][4];
  #pragma unroll
  for (int mf = 0; mf < 4; mf++)
    #pragma unroll
    for (int nf = 0; nf < 4; nf++) {
      accA[mf][nf] = (f32x4){0.f, 0.f, 0.f, 0.f};
      accB[mf][nf] = (f32x4){0.f, 0.f, 0.f, 0.f};
    }

  // stage(qs, buf): 8 async wave-loads, lane->16B identity layout
  #define STAGE(qs_, buf_)                                                              \
    {                                                                                   \
      int _q = (qs_) * 32 + quad * 8;                                                   \
      _Pragma("unroll")                                                                 \
      for (int nf = 0; nf < 4; nf++) {                                                  \
        size_t rowD = (size_t)((b << 8) + dq + nf * 16 + col);                          \
        gload16(QT + (rowD << 9) + _q, &sb[w][buf_][nf][0]);                            \
        gload16(TT + (rowD << 9) + _q, &sb[w][buf_][4 + nf][0]);                        \
      }                                                                                 \
    }

  bf16x8 pa[4], paN[4];
  #pragma unroll
  for (int mf = 0; mf < 4; mf++)
    pa[mf] = ldb8(Pt + (((size_t)(b * 64 + ct * 4 + mf) * 16 + 0) << 9) + lane * 8);
  STAGE(0, 0);
  __syncthreads();

  for (int qs = 0; qs < 16; qs++) {
    int bufr = qs & 1;
    if (qs < 15) {
      STAGE(qs + 1, bufr ^ 1);
      #pragma unroll
      for (int mf = 0; mf < 4; mf++)
        paN[mf] = ldb8(Pt + (((size_t)(b * 64 + ct * 4 + mf) * 16 + qs + 1) << 9) + lane * 8);
    }
    bf16x8 bq[4], bt[4];
    #pragma unroll
    for (int nf = 0; nf < 4; nf++) {
      bq[nf] = ldb8(&sb[w][bufr][nf][lane * 8]);
      bt[nf] = ldb8(&sb[w][bufr][4 + nf][lane * 8]);
    }
    #pragma unroll
    for (int mf = 0; mf < 4; mf++)
      #pragma unroll
      for (int nf = 0; nf < 4; nf++) {
        accA[mf][nf] = MFMA16(pa[mf], bq[nf], accA[mf][nf]);
        accB[mf][nf] = MFMA16(pa[mf], bt[nf], accB[mf][nf]);
      }
    if (qs < 15) {
      #pragma unroll
      for (int mf = 0; mf < 4; mf++) pa[mf] = paN[mf];
    }
    __syncthreads();
  }

  // epilogue: scale by 1/rowL, multiply with C, write 4 chunks transposed
  float rInv[4][4];
  #pragma unroll
  for (int mf = 0; mf < 4; mf++) {
    float4 rv = *(const float4*)(rowL + ((size_t)b << 10) + ct * 64 + mf * 16 + quad * 4);
    rInv[mf][0] = 1.0f / rv.x; rInv[mf][1] = 1.0f / rv.y;
    rInv[mf][2] = 1.0f / rv.z; rInv[mf][3] = 1.0f / rv.w;
  }
  size_t outB = (size_t)b << 20;
  #pragma unroll
  for (int mf = 0; mf < 4; mf++) {
    int cc = ct * 64 + mf * 16 + quad * 4;
    #pragma unroll
    for (int nf = 0; nf < 4; nf++) {
      int d = dq + nf * 16 + col;
      float4 vC, vA, vCA, vCB;
      #pragma unroll
      for (int r = 0; r < 4; r++) {
        float Cv = C[((size_t)(cc + r) * BB + b) * DDim + d];
        float Av = accA[mf][nf][r] * rInv[mf][r];
        float Bv = accB[mf][nf][r] * rInv[mf][r];
        ((float*)&vC)[r] = Cv;
        ((float*)&vA)[r] = Av;
        ((float*)&vCA)[r] = Cv * Av;
        ((float*)&vCB)[r] = Cv * Bv;
      }
      float* o0 = out + outB + (size_t)d * LCc + cc;
      *(float4*)(o0) = vC;
      *(float4*)(o0 + (size_t)DDim * LCc) = vA;
      *(float4*)(o0 + 2 * (size_t)DDim * LCc) = vCA;
      *(float4*)(o0 + 3 * (size_t)DDim * LCc) = vCB;
    }
  }
  #undef STAGE
}

// ---------------------------------------------------------------------------
extern "C" void kernel_launch(void* const* d_in, const int* in_sizes, int n_in,
                              void* d_out, int out_size, void* d_ws, size_t ws_size,
                              hipStream_t stream) {
  const float* C    = (const float*)d_in[0];
  const float* Q    = (const float*)d_in[1];
  const float* w4C  = (const float*)d_in[2];
  const float* w4Q  = (const float*)d_in[3];
  const float* w4mlu= (const float*)d_in[4];
  const float* bias = (const float*)d_in[5];
  float* out = (float*)d_out;
  char* ws = (char*)d_ws;

  // workspace layout (~161 MiB; TT aliases Qb — Qb dead after k_P)
  unsigned short* Cw = (unsigned short*)(ws);                       // 33554432
  unsigned short* CT = (unsigned short*)(ws + 33554432);            // 33554432
  unsigned short* Qb = (unsigned short*)(ws + 67108864);            // 16777216
  unsigned short* TT = Qb;                                          // alias
  unsigned short* QT = (unsigned short*)(ws + 83886080);            // 16777216
  unsigned short* Pt = (unsigned short*)(ws + 100663296);           // 67108864
  float* rowAdd = (float*)(ws + 167772160);                         //   262144
  float* colAdd = (float*)(ws + 168034304);                         //   131072
  float* rowL   = (float*)(ws + 168165376);                         //   262144
  float* colL   = (float*)(ws + 168427520);                         //   131072

  prep_F<<<dim3(24, BB), 256, 0, stream>>>(C, Q, w4C, w4Q, w4mlu, bias,
                                           Cw, CT, rowAdd, Qb, QT, colAdd, colL);
  k_P<<<BB * 16, 256, 0, stream>>>(Cw, Qb, rowAdd, colAdd, Pt, rowL, colL);
  k_T<<<BB * 16, 256, 0, stream>>>(Pt, CT, colL, TT);
  k_AB<<<BB * 16, 256, 0, stream>>>(Pt, QT, TT, rowL, C, out);
}